// Round 5
// baseline (13227.246 us; speedup 1.0000x reference)
//
#include <hip/hip_runtime.h>
#include <hip/hip_bf16.h>
#include <stdint.h>

#define TT 512
#define HD 512
#define BB 32
#define MM (BB*TT)     // 16384 rows (b*T+t)
#define NG 3072        // 2 dirs * 3 gates * 512
#define WGD 8          // workgroups per direction
#define CPW 64         // h columns per workgroup (4 compute waves x 16)

typedef short short8 __attribute__((ext_vector_type(8)));
typedef float f32x4 __attribute__((ext_vector_type(4)));
typedef float f32x2 __attribute__((ext_vector_type(2)));
typedef unsigned short u16;
typedef unsigned int u32;

__device__ __forceinline__ u16 f2bf(float f) {
  __hip_bfloat16 h = __float2bfloat16(f);
  union { __hip_bfloat16 h; u16 u; } c; c.h = h; return c.u;
}
__device__ __forceinline__ float bf2f(u16 u) {
  union { u32 i; float f; } c; c.i = ((u32)u) << 16; return c.f;
}
__device__ __forceinline__ float sigmf(float x) {
  return 1.0f / (1.0f + __expf(-x));
}

// ---------------- f32 -> bf16 convert ----------------
__global__ __launch_bounds__(256) void cvt_bf16(const float* __restrict__ in,
                                                u16* __restrict__ out, int n8) {
  int i = blockIdx.x * 256 + threadIdx.x;
  if (i >= n8) return;
  const float4* p = (const float4*)in;
  float4 a = p[2*i], b = p[2*i+1];
  union { short8 v; u16 u[8]; } o;
  o.u[0]=f2bf(a.x); o.u[1]=f2bf(a.y); o.u[2]=f2bf(a.z); o.u[3]=f2bf(a.w);
  o.u[4]=f2bf(b.x); o.u[5]=f2bf(b.y); o.u[6]=f2bf(b.z); o.u[7]=f2bf(b.w);
  ((short8*)out)[i] = o.v;
}

// ---------------- gx GEMM (unchanged from R4) ----------------
__global__ __launch_bounds__(256) void gemm_gx(const u16* __restrict__ A,
                                               const u16* __restrict__ Bw,
                                               char* __restrict__ gxout,
                                               int K, int gxf32) {
  __shared__ __align__(16) u16 lA[128*32];
  __shared__ __align__(16) u16 lB[128*32];
  const int tid = threadIdx.x;
  const int lane = tid & 63;
  const int wid = tid >> 6;
  const int wr = wid >> 1, wc = wid & 1;
  const int bm = blockIdx.y * 128, bn = blockIdx.x * 128;
  const int col = lane & 15, kg = lane >> 4;

  f32x4 acc[4][4];
#pragma unroll
  for (int m = 0; m < 4; ++m)
#pragma unroll
    for (int n = 0; n < 4; ++n) acc[m][n] = (f32x4){0.f,0.f,0.f,0.f};

  const int nkt = K >> 5;
  for (int kt = 0; kt < nkt; ++kt) {
    short8 ra[2], rb[2];
    const int kb = kt * 32;
#pragma unroll
    for (int p = 0; p < 2; ++p) {
      int id = p*256 + tid;
      int row = id >> 2, c = id & 3;
      ra[p] = *(const short8*)(A  + (size_t)(bm+row)*K + kb + c*8);
      rb[p] = *(const short8*)(Bw + (size_t)(bn+row)*K + kb + c*8);
    }
    __syncthreads();
#pragma unroll
    for (int p = 0; p < 2; ++p) {
      int id = p*256 + tid;
      int row = id >> 2, c = id & 3;
      int off = row*64 + ((c ^ ((row>>1)&3))*16);
      *(short8*)((char*)lA + off) = ra[p];
      *(short8*)((char*)lB + off) = rb[p];
    }
    __syncthreads();
    short8 af[4], bf[4];
#pragma unroll
    for (int m = 0; m < 4; ++m) {
      int row = wr*64 + m*16 + col;
      af[m] = *(short8*)((char*)lA + row*64 + ((kg ^ ((row>>1)&3))*16));
    }
#pragma unroll
    for (int n = 0; n < 4; ++n) {
      int row = wc*64 + n*16 + col;
      bf[n] = *(short8*)((char*)lB + row*64 + ((kg ^ ((row>>1)&3))*16));
    }
#pragma unroll
    for (int m = 0; m < 4; ++m)
#pragma unroll
      for (int n = 0; n < 4; ++n)
        acc[m][n] = __builtin_amdgcn_mfma_f32_16x16x32_bf16(af[m], bf[n], acc[m][n], 0,0,0);
  }
#pragma unroll
  for (int m = 0; m < 4; ++m)
#pragma unroll
    for (int n = 0; n < 4; ++n)
#pragma unroll
      for (int r = 0; r < 4; ++r) {
        int rowg = bm + wr*64 + m*16 + kg*4 + r;
        int colg = bn + wc*64 + n*16 + col;
        float v = acc[m][n][r];
        if (gxf32) ((float*)gxout)[(size_t)rowg*NG + colg] = v;
        else       ((u16*)gxout)[(size_t)rowg*NG + colg] = f2bf(v);
      }
}

// ---------------- persistent BiGRU recurrence (wave-fused gates) ----------------
// grid = 16 WGs (512 thr, 8 waves): dir = wg>>3, jb = wg&7 -> cols [jb*64, jb*64+64).
// Waves 0..3: compute wave w owns output cols jb*64+w*16..+16 for ALL 3 gates.
//   w_hh fragments for r,z,n in registers (3x16 short8 = 96 VGPR). MFMA C-layout
//   (col=lane&15, row=kg*4+r) => each lane holds r,z,n accs for its own (b,col)
//   pairs -> gates computed fully in-register, h_prev lane-resident.
//   Publish: 8 agent-scope u16 stores -> LLC; per-WAVE flag released immediately
//   (drains only this wave's stores). No gh LDS round trip, no barriers C/D.
// Wave 7: dedicated flag poller (arrives at poll earliest). All waves stage.
__global__ __launch_bounds__(512, 2) void bigru_rec(const char* __restrict__ gx,
                                                    const u16* __restrict__ whhb,
                                                    const float* __restrict__ b_ih,
                                                    const float* __restrict__ b_hh,
                                                    char* __restrict__ out,
                                                    u16* __restrict__ himg,   // [2][2][32][512]
                                                    u32* __restrict__ flags,  // [2][32] stride 16 dwords
                                                    int gxf32, int outf32) {
  const int wg = blockIdx.x;
  const int dir = wg >> 3;
  const int jb = wg & 7;
  const int tid = threadIdx.x;
  const int lane = tid & 63;
  const int wv = tid >> 6;
  const int col = lane & 15, kg = lane >> 4;

  __shared__ __align__(16) u16 hstage[32*512];          // 32 KB, swizzled
  __shared__ __align__(16) float gxlf[2][3][32][64];    // 48 KB (f32 path, dbuf)
  __shared__ __align__(16) u16  gxlb[2][3][32][64];     // 24 KB (bf16 path, dbuf)
  __shared__ float bihs[3][64], bhhs[3][64];

  // --- one-time: w_hh fragments for all 3 gates (compute waves 0..3) ---
  short8 bfr[16], bfz[16], bfn[16];
  const int gcol = jb*CPW + wv*16 + col;   // valid for wv<4
  if (wv < 4) {
    const u16* w0 = whhb + (size_t)(dir*1536 + 0*512 + gcol) * 512;
    const u16* w1 = whhb + (size_t)(dir*1536 + 1*512 + gcol) * 512;
    const u16* w2 = whhb + (size_t)(dir*1536 + 2*512 + gcol) * 512;
#pragma unroll
    for (int kc = 0; kc < 16; ++kc) {
      bfr[kc] = *(const short8*)(w0 + kc*32 + kg*8);
      bfz[kc] = *(const short8*)(w1 + kc*32 + kg*8);
      bfn[kc] = *(const short8*)(w2 + kc*32 + kg*8);
    }
  }
  if (tid < 192) {
    int g = tid >> 6, j = tid & 63;
    bihs[g][j] = b_ih[dir*1536 + g*512 + jb*CPW + j];
    bhhs[g][j] = b_hh[dir*1536 + g*512 + jb*CPW + j];
  }
  __syncthreads();

  float hp[2][4], hv_[2][4];
#pragma unroll
  for (int m = 0; m < 2; ++m)
#pragma unroll
    for (int r = 0; r < 4; ++r) hp[m][r] = 0.f;

  u32* dirflags = flags + (size_t)dir * 32 * 16;
  u32* myflag = dirflags + (size_t)(jb * 4 + wv) * 16;

  for (int t = 0; t < TT; ++t) {
    const int tt = dir ? (TT - 1 - t) : t;
    const int par = t & 1;

    // --- stage gx[tt] -> LDS (parity double-buffered; L2-warm reads) ---
    if (gxf32) {
      const float* gxf = (const float*)gx;
#pragma unroll
      for (int q = 0; q < 3; ++q) {
        int cid = q*512 + tid;           // 1536 float4 chunks
        int b = cid/48, rem = cid%48, g = rem>>4, qc = rem&15;
        float4 v = *(const float4*)(gxf + (size_t)(b*TT+tt)*NG + dir*1536 + g*512 + jb*CPW + qc*4);
        *(float4*)&gxlf[par][g][b][qc*4] = v;
      }
    } else {
      const u16* gxb = (const u16*)gx;
#pragma unroll
      for (int q = 0; q < 2; ++q) {
        int cid = q*512 + tid;           // 768 short8 chunks
        if (cid < 768) {
          int b = cid/24, rem = cid%24, g = rem>>3, qc = rem&7;
          short8 v = *(const short8*)(gxb + (size_t)(b*TT+tt)*NG + dir*1536 + g*512 + jb*CPW + qc*8);
          *(short8*)&gxlb[par][g][b][qc*8] = v;
        }
      }
    }

    // --- wave 7 polls the 32 per-wave producer flags of this dir ---
    if (t > 0 && wv == 7) {
      const u32 need = (u32)t;
      const u32* fp = dirflags + (size_t)lane * 16;
      int iter = 0;
      while (iter++ < (1 << 24)) {
        u32 v = (lane < 32)
              ? __hip_atomic_load(fp, __ATOMIC_RELAXED, __HIP_MEMORY_SCOPE_AGENT)
              : need;
        if (__all(v >= need)) break;
        __builtin_amdgcn_s_sleep(1);
      }
    }
    __syncthreads();   // (A) flags confirmed; prev-step hstage reads done

    // --- stage h image via agent-scope bypass loads -> swizzled LDS ---
    const u32* imgr = (const u32*)(himg + ((size_t)dir*2 + par) * 32 * 512);
#pragma unroll
    for (int p = 0; p < 16; ++p) {
      int id = p*512 + tid;              // 8192 u32 = 32 rows x 256
      int row = id >> 8, dcol = id & 255;
      u32 hv = __hip_atomic_load(imgr + row*256 + dcol, __ATOMIC_RELAXED, __HIP_MEMORY_SCOPE_AGENT);
      int c = dcol >> 2;
      *(u32*)((char*)hstage + row*1024 + (((c ^ (row & 7)) << 4) | ((dcol & 3) << 2))) = hv;
    }
    __syncthreads();   // (B)

    if (wv < 4) {
      // --- MFMA: 3 gates x 2 M-tiles x 16 kc ---
      f32x4 ar[2], az[2], an_[2];
#pragma unroll
      for (int m = 0; m < 2; ++m) { ar[m] = (f32x4){0.f,0.f,0.f,0.f}; az[m] = ar[m]; an_[m] = ar[m]; }
#pragma unroll
      for (int kc = 0; kc < 16; ++kc) {
        int c = kc*4 + kg;
        short8 a0 = *(short8*)((char*)hstage + col*1024      + ((c ^ (col & 7)) << 4));
        short8 a1 = *(short8*)((char*)hstage + (16+col)*1024 + ((c ^ (col & 7)) << 4));
        ar[0]  = __builtin_amdgcn_mfma_f32_16x16x32_bf16(a0, bfr[kc], ar[0], 0,0,0);
        ar[1]  = __builtin_amdgcn_mfma_f32_16x16x32_bf16(a1, bfr[kc], ar[1], 0,0,0);
        az[0]  = __builtin_amdgcn_mfma_f32_16x16x32_bf16(a0, bfz[kc], az[0], 0,0,0);
        az[1]  = __builtin_amdgcn_mfma_f32_16x16x32_bf16(a1, bfz[kc], az[1], 0,0,0);
        an_[0] = __builtin_amdgcn_mfma_f32_16x16x32_bf16(a0, bfn[kc], an_[0], 0,0,0);
        an_[1] = __builtin_amdgcn_mfma_f32_16x16x32_bf16(a1, bfn[kc], an_[1], 0,0,0);
      }

      // --- gates fully in-register; publish h_new (agent -> LLC) ---
      u16* img2 = himg + ((size_t)dir*2 + ((t + 1) & 1)) * 32 * 512;
      const int lcol = wv*16 + col;
#pragma unroll
      for (int m = 0; m < 2; ++m)
#pragma unroll
        for (int rr = 0; rr < 4; ++rr) {
          int b = m*16 + kg*4 + rr;
          float xr, xz, xn;
          if (gxf32) {
            xr = gxlf[par][0][b][lcol]; xz = gxlf[par][1][b][lcol]; xn = gxlf[par][2][b][lcol];
          } else {
            xr = bf2f(gxlb[par][0][b][lcol]); xz = bf2f(gxlb[par][1][b][lcol]); xn = bf2f(gxlb[par][2][b][lcol]);
          }
          float rg = sigmf(xr + bihs[0][lcol] + ar[m][rr]  + bhhs[0][lcol]);
          float zg = sigmf(xz + bihs[1][lcol] + az[m][rr]  + bhhs[1][lcol]);
          float ng = tanhf(xn + bihs[2][lcol] + rg*(an_[m][rr] + bhhs[2][lcol]));
          float hv = (1.f - zg)*ng + zg*hp[m][rr];
          hp[m][rr] = hv; hv_[m][rr] = hv;
          __hip_atomic_store(img2 + b*512 + gcol, f2bf(hv),
                             __ATOMIC_RELAXED, __HIP_MEMORY_SCOPE_AGENT);
        }

      // --- per-wave flag: release drains ONLY this wave's 8 publish stores ---
      if (lane == 0)
        __hip_atomic_store(myflag, (u32)(t + 1), __ATOMIC_RELEASE, __HIP_MEMORY_SCOPE_AGENT);

      // --- out stores after flag (plain cached stores; ack from local L2) ---
#pragma unroll
      for (int m = 0; m < 2; ++m)
#pragma unroll
        for (int rr = 0; rr < 4; ++rr) {
          int b = m*16 + kg*4 + rr;
          size_t oi = (size_t)(b*TT + tt)*1024 + dir*512 + gcol;
          if (outf32) ((float*)out)[oi] = hv_[m][rr];
          else        ((u16*)out)[oi]   = f2bf(hv_[m][rr]);
        }
    }
  }
}

// ---------------- host ----------------
extern "C" void kernel_launch(void* const* d_in, const int* in_sizes, int n_in,
                              void* d_out, int out_size, void* d_ws, size_t ws_size,
                              hipStream_t stream) {
  (void)in_sizes; (void)n_in; (void)out_size;
  const float* x    = (const float*)d_in[0];
  const float* wih0 = (const float*)d_in[1];
  const float* whh0 = (const float*)d_in[2];
  const float* bih0 = (const float*)d_in[3];
  const float* bhh0 = (const float*)d_in[4];
  const float* wih1 = (const float*)d_in[5];
  const float* whh1 = (const float*)d_in[6];
  const float* bih1 = (const float*)d_in[7];
  const float* bhh1 = (const float*)d_in[8];

  char* ws = (char*)d_ws;
  size_t off = 0;
  auto alloc = [&](size_t bytes) { size_t o = off; off += (bytes + 255) & ~(size_t)255; return o; };
  size_t off_xb   = alloc((size_t)MM * 512 * 2);       // x bf16
  size_t off_wih0 = alloc((size_t)3072 * 512 * 2);
  size_t off_wih1 = alloc((size_t)3072 * 1024 * 2);
  size_t off_whh0 = alloc((size_t)3072 * 512 * 2);
  size_t off_whh1 = alloc((size_t)3072 * 512 * 2);
  size_t off_h0   = alloc((size_t)MM * 1024 * 2);      // layer-0 output bf16
  size_t off_sync = alloc(131072 + 4096);              // h images (128KB) + flags (4KB)
  size_t off_gx   = off;                               // gx last
  int gxf32 = (ws_size >= off_gx + (size_t)MM * NG * 4) ? 1 : 0;

  u16* xb    = (u16*)(ws + off_xb);
  u16* wih0b = (u16*)(ws + off_wih0);
  u16* wih1b = (u16*)(ws + off_wih1);
  u16* whh0b = (u16*)(ws + off_whh0);
  u16* whh1b = (u16*)(ws + off_whh1);
  u16* h0b   = (u16*)(ws + off_h0);
  u16* himg  = (u16*)(ws + off_sync);
  u32* flags = (u32*)(ws + off_sync + 131072);
  char* gx   = ws + off_gx;

  cvt_bf16<<<4096, 256, 0, stream>>>(x,    xb,    MM*512/8);
  cvt_bf16<<<768,  256, 0, stream>>>(wih0, wih0b, 3072*512/8);
  cvt_bf16<<<1536, 256, 0, stream>>>(wih1, wih1b, 3072*1024/8);
  cvt_bf16<<<768,  256, 0, stream>>>(whh0, whh0b, 3072*512/8);
  cvt_bf16<<<768,  256, 0, stream>>>(whh1, whh1b, 3072*512/8);

  dim3 ggrid(NG/128, MM/128);   // (24, 128)

  // layer 0
  gemm_gx<<<ggrid, 256, 0, stream>>>(xb, wih0b, gx, 512, gxf32);
  (void)hipMemsetAsync(ws + off_sync, 0, 131072 + 4096, stream);
  bigru_rec<<<16, 512, 0, stream>>>(gx, whh0b, bih0, bhh0, (char*)h0b, himg, flags, gxf32, 0);

  // layer 1
  gemm_gx<<<ggrid, 256, 0, stream>>>(h0b, wih1b, gx, 1024, gxf32);
  (void)hipMemsetAsync(ws + off_sync, 0, 131072 + 4096, stream);
  bigru_rec<<<16, 512, 0, stream>>>(gx, whh1b, bih1, bhh1, (char*)d_out, himg, flags, gxf32, 1);
}

// Round 6
// 5074.173 us; speedup vs baseline: 2.6068x; 2.6068x over previous
//
#include <hip/hip_runtime.h>
#include <hip/hip_bf16.h>
#include <stdint.h>

#define TT 512
#define HD 512
#define BB 32
#define MM (BB*TT)     // 16384 rows (b*T+t)
#define NG 3072        // 2 dirs * 3 gates * 512
#define WGD 16         // workgroups per direction
#define CPW 32         // h columns per workgroup

typedef short short8 __attribute__((ext_vector_type(8)));
typedef float f32x4 __attribute__((ext_vector_type(4)));
typedef float f32x2 __attribute__((ext_vector_type(2)));
typedef unsigned short u16;
typedef unsigned int u32;
typedef unsigned long long u64;

__device__ __forceinline__ u16 f2bf(float f) {
  __hip_bfloat16 h = __float2bfloat16(f);
  union { __hip_bfloat16 h; u16 u; } c; c.h = h; return c.u;
}
__device__ __forceinline__ float bf2f(u16 u) {
  union { u32 i; float f; } c; c.i = ((u32)u) << 16; return c.f;
}
__device__ __forceinline__ float sigmf(float x) {
  return 1.0f / (1.0f + __expf(-x));
}
__device__ __forceinline__ float tanhff(float x) {
  float a = __expf(2.0f * x);          // inf -> 1, 0 -> -1 : graceful
  return 1.0f - 2.0f / (a + 1.0f);
}

// ---------------- f32 -> bf16 convert ----------------
__global__ __launch_bounds__(256) void cvt_bf16(const float* __restrict__ in,
                                                u16* __restrict__ out, int n8) {
  int i = blockIdx.x * 256 + threadIdx.x;
  if (i >= n8) return;
  const float4* p = (const float4*)in;
  float4 a = p[2*i], b = p[2*i+1];
  union { short8 v; u16 u[8]; } o;
  o.u[0]=f2bf(a.x); o.u[1]=f2bf(a.y); o.u[2]=f2bf(a.z); o.u[3]=f2bf(a.w);
  o.u[4]=f2bf(b.x); o.u[5]=f2bf(b.y); o.u[6]=f2bf(b.z); o.u[7]=f2bf(b.w);
  ((short8*)out)[i] = o.v;
}

// ---------------- gx GEMM (unchanged) ----------------
__global__ __launch_bounds__(256) void gemm_gx(const u16* __restrict__ A,
                                               const u16* __restrict__ Bw,
                                               char* __restrict__ gxout,
                                               int K, int gxf32) {
  __shared__ __align__(16) u16 lA[128*32];
  __shared__ __align__(16) u16 lB[128*32];
  const int tid = threadIdx.x;
  const int lane = tid & 63;
  const int wid = tid >> 6;
  const int wr = wid >> 1, wc = wid & 1;
  const int bm = blockIdx.y * 128, bn = blockIdx.x * 128;
  const int col = lane & 15, kg = lane >> 4;

  f32x4 acc[4][4];
#pragma unroll
  for (int m = 0; m < 4; ++m)
#pragma unroll
    for (int n = 0; n < 4; ++n) acc[m][n] = (f32x4){0.f,0.f,0.f,0.f};

  const int nkt = K >> 5;
  for (int kt = 0; kt < nkt; ++kt) {
    short8 ra[2], rb[2];
    const int kb = kt * 32;
#pragma unroll
    for (int p = 0; p < 2; ++p) {
      int id = p*256 + tid;
      int row = id >> 2, c = id & 3;
      ra[p] = *(const short8*)(A  + (size_t)(bm+row)*K + kb + c*8);
      rb[p] = *(const short8*)(Bw + (size_t)(bn+row)*K + kb + c*8);
    }
    __syncthreads();
#pragma unroll
    for (int p = 0; p < 2; ++p) {
      int id = p*256 + tid;
      int row = id >> 2, c = id & 3;
      int off = row*64 + ((c ^ ((row>>1)&3))*16);
      *(short8*)((char*)lA + off) = ra[p];
      *(short8*)((char*)lB + off) = rb[p];
    }
    __syncthreads();
    short8 af[4], bf[4];
#pragma unroll
    for (int m = 0; m < 4; ++m) {
      int row = wr*64 + m*16 + col;
      af[m] = *(short8*)((char*)lA + row*64 + ((kg ^ ((row>>1)&3))*16));
    }
#pragma unroll
    for (int n = 0; n < 4; ++n) {
      int row = wc*64 + n*16 + col;
      bf[n] = *(short8*)((char*)lB + row*64 + ((kg ^ ((row>>1)&3))*16));
    }
#pragma unroll
    for (int m = 0; m < 4; ++m)
#pragma unroll
      for (int n = 0; n < 4; ++n)
        acc[m][n] = __builtin_amdgcn_mfma_f32_16x16x32_bf16(af[m], bf[n], acc[m][n], 0,0,0);
  }
#pragma unroll
  for (int m = 0; m < 4; ++m)
#pragma unroll
    for (int n = 0; n < 4; ++n)
#pragma unroll
      for (int r = 0; r < 4; ++r) {
        int rowg = bm + wr*64 + m*16 + kg*4 + r;
        int colg = bn + wc*64 + n*16 + col;
        float v = acc[m][n][r];
        if (gxf32) ((float*)gxout)[(size_t)rowg*NG + colg] = v;
        else       ((u16*)gxout)[(size_t)rowg*NG + colg] = f2bf(v);
      }
}

// ---------------- persistent BiGRU recurrence (R4 skeleton + parallel drain) ----
// grid = 32 WGs (512 thr, 8 waves): dir = wg>>4, jb = wg&15 -> cols [jb*32,+32).
// Waves 0..5 MFMA (gate g=wv>>1, col-half ch=wv&1; 64 VGPR weights). All 8 waves
// do gates (2 (b,j) pairs/thread). Publish u32 packed -> LLC. Per-wave vmcnt
// drain -> LDS counter -> 8th wave releases the single WG flag (no barrier D).
__global__ __launch_bounds__(512, 2) void bigru_rec(const char* __restrict__ gx,
                                                    const u16* __restrict__ whhb,
                                                    const float* __restrict__ b_ih,
                                                    const float* __restrict__ b_hh,
                                                    char* __restrict__ out,
                                                    u16* __restrict__ himg,   // [2][2][32][512]
                                                    u32* __restrict__ flags,  // [2][16] stride 16 dwords
                                                    int gxf32, int outf32) {
  const int wg = blockIdx.x;
  const int dir = wg >> 4;
  const int jb = wg & 15;
  const int tid = threadIdx.x;
  const int lane = tid & 63;
  const int wv = tid >> 6;
  const int col = lane & 15, kg = lane >> 4;

  __shared__ __align__(16) u16 hstage[32*512];     // 32 KB, swizzled
  __shared__ float gh[3][32][33];                  // padded: no bank conflicts
  __shared__ __align__(16) char gxmem[2][12288];   // 24 KB, parity dbuf (f32 or bf16)
  __shared__ float bihs[3][32], bhhs[3][32];
  __shared__ u32 lctr;

  // --- one-time: w_hh B-fragments (waves 0..5: gate g=wv>>1, half ch=wv&1) ---
  short8 bfrag[16];
  if (wv < 6) {
    const int g = wv >> 1, ch = wv & 1;
    const u16* wrow = whhb + (size_t)(dir*1536 + g*512 + jb*CPW + ch*16 + col) * 512;
#pragma unroll
    for (int kc = 0; kc < 16; ++kc)
      bfrag[kc] = *(const short8*)(wrow + kc*32 + kg*8);
  }
  if (tid < 96) {
    int g = tid >> 5, j = tid & 31;
    bihs[g][j] = b_ih[dir*1536 + g*512 + jb*CPW + j];
    bhhs[g][j] = b_hh[dir*1536 + g*512 + jb*CPW + j];
  }
  if (tid == 0) lctr = 0;
  __syncthreads();

  const int gb = tid >> 4, gj0 = (tid & 15) * 2;
  float hp0 = 0.f, hp1 = 0.f;

  u32* dirflags = flags + (size_t)dir * WGD * 16;
  u32* myflag = dirflags + (size_t)jb * 16;

  for (int t = 0; t < TT; ++t) {
    const int tt = dir ? (TT - 1 - t) : t;
    const int par = t & 1;
    float* gxlF = (float*)gxmem[par];
    u16*   gxlB = (u16*)gxmem[par];

    // --- stage gx[tt] -> LDS (parity dbuf) ---
    if (gxf32) {
      const float* gxf = (const float*)gx;
      { int cid = tid; int b = cid/24, rem = cid%24, g = rem>>3, q = rem&7;
        float4 v = *(const float4*)(gxf + (size_t)(b*TT+tt)*NG + dir*1536 + g*512 + jb*CPW + q*4);
        *(float4*)&gxlF[g*1024 + b*32 + q*4] = v; }
      if (tid < 256) {
        int cid = 512 + tid; int b = cid/24, rem = cid%24, g = rem>>3, q = rem&7;
        float4 v = *(const float4*)(gxf + (size_t)(b*TT+tt)*NG + dir*1536 + g*512 + jb*CPW + q*4);
        *(float4*)&gxlF[g*1024 + b*32 + q*4] = v; }
    } else {
      if (tid < 384) {
        const u16* gxb = (const u16*)gx;
        int b = tid/12, rem = tid%12, g = rem>>2, q = rem&3;
        short8 v = *(const short8*)(gxb + (size_t)(b*TT+tt)*NG + dir*1536 + g*512 + jb*CPW + q*8);
        *(short8*)&gxlB[g*1024 + b*32 + q*8] = v;
      }
    }

    // --- wave 0 polls the 16 WG flags of this dir (no sleep: latency IS the interval) ---
    if (t > 0 && wv == 0) {
      const u32 need = (u32)t;
      const u32* fp = dirflags + (size_t)lane * 16;
      int iter = 0;
      while (iter++ < (1 << 24)) {
        u32 v = (lane < WGD)
              ? __hip_atomic_load(fp, __ATOMIC_RELAXED, __HIP_MEMORY_SCOPE_AGENT)
              : need;
        if (__all(v >= need)) break;
      }
    }
    __syncthreads();   // (A) flags confirmed; prev-step hstage reads done

    // --- read h image via agent-scope u64 bypass loads -> swizzled LDS ---
    const u64* imgr = (const u64*)(himg + ((size_t)dir*2 + par) * 32 * 512);
#pragma unroll
    for (int p = 0; p < 8; ++p) {
      int id = p*512 + tid;              // 4096 u64 = 32 rows x 128
      int row = id >> 7, d2 = id & 127;
      u64 hv = __hip_atomic_load(imgr + row*128 + d2, __ATOMIC_RELAXED, __HIP_MEMORY_SCOPE_AGENT);
      int c = d2 >> 1;
      *(u64*)((char*)hstage + row*1024 + (((c ^ (row & 7)) << 4) | ((d2 & 1) << 3))) = hv;
    }
    __syncthreads();   // (B)

    // --- MFMA: gh[g][b][jloc] over K=512 (waves 0..5) ---
    if (wv < 6) {
      const int g = wv >> 1, ch = wv & 1;
      f32x4 acc0 = (f32x4){0.f,0.f,0.f,0.f};
      f32x4 acc1 = (f32x4){0.f,0.f,0.f,0.f};
#pragma unroll
      for (int kc = 0; kc < 16; ++kc) {
        int c = kc*4 + kg;
        short8 a0 = *(short8*)((char*)hstage + col*1024      + ((c ^ (col & 7)) << 4));
        short8 a1 = *(short8*)((char*)hstage + (16+col)*1024 + ((c ^ (col & 7)) << 4));
        acc0 = __builtin_amdgcn_mfma_f32_16x16x32_bf16(a0, bfrag[kc], acc0, 0,0,0);
        acc1 = __builtin_amdgcn_mfma_f32_16x16x32_bf16(a1, bfrag[kc], acc1, 0,0,0);
      }
#pragma unroll
      for (int r = 0; r < 4; ++r) {
        gh[g][kg*4 + r][ch*16 + col]      = acc0[r];
        gh[g][16 + kg*4 + r][ch*16 + col] = acc1[r];
      }
    }
    __syncthreads();   // (C)

    // --- gates: thread -> (b=gb, j=gj0, gj0+1), fully parallel across 8 waves ---
    float hv0, hv1; u32 pv;
    {
      float xr0, xz0, xn0, xr1, xz1, xn1;
      if (gxf32) {
        xr0 = gxlF[gb*32+gj0];        xz0 = gxlF[1024+gb*32+gj0];   xn0 = gxlF[2048+gb*32+gj0];
        xr1 = gxlF[gb*32+gj0+1];      xz1 = gxlF[1024+gb*32+gj0+1]; xn1 = gxlF[2048+gb*32+gj0+1];
      } else {
        xr0 = bf2f(gxlB[gb*32+gj0]);   xz0 = bf2f(gxlB[1024+gb*32+gj0]);   xn0 = bf2f(gxlB[2048+gb*32+gj0]);
        xr1 = bf2f(gxlB[gb*32+gj0+1]); xz1 = bf2f(gxlB[1024+gb*32+gj0+1]); xn1 = bf2f(gxlB[2048+gb*32+gj0+1]);
      }
      float r0 = sigmf(xr0 + bihs[0][gj0]   + gh[0][gb][gj0]   + bhhs[0][gj0]);
      float z0 = sigmf(xz0 + bihs[1][gj0]   + gh[1][gb][gj0]   + bhhs[1][gj0]);
      float n0 = tanhff(xn0 + bihs[2][gj0]  + r0*(gh[2][gb][gj0] + bhhs[2][gj0]));
      hv0 = (1.f - z0)*n0 + z0*hp0;
      float r1 = sigmf(xr1 + bihs[0][gj0+1] + gh[0][gb][gj0+1] + bhhs[0][gj0+1]);
      float z1 = sigmf(xz1 + bihs[1][gj0+1] + gh[1][gb][gj0+1] + bhhs[1][gj0+1]);
      float n1 = tanhff(xn1 + bihs[2][gj0+1] + r1*(gh[2][gb][gj0+1] + bhhs[2][gj0+1]));
      hv1 = (1.f - z1)*n1 + z1*hp1;
      hp0 = hv0; hp1 = hv1;

      // publish h_new pair to next image (agent -> LLC)
      u32* img2 = (u32*)(himg + ((size_t)dir*2 + ((t + 1) & 1)) * 32 * 512);
      pv = (u32)f2bf(hv0) | ((u32)f2bf(hv1) << 16);
      __hip_atomic_store(img2 + gb*256 + jb*16 + (tid & 15), pv,
                         __ATOMIC_RELAXED, __HIP_MEMORY_SCOPE_AGENT);
    }

    // --- per-wave drain (parallel) -> LDS counter -> 8th wave releases WG flag ---
    asm volatile("s_waitcnt vmcnt(0)" ::: "memory");
    if (lane == 0) {
      u32 old = atomicAdd(&lctr, 1u);
      if (old == (u32)(t*8 + 7))
        __hip_atomic_store(myflag, (u32)(t + 1), __ATOMIC_RELAXED, __HIP_MEMORY_SCOPE_AGENT);
    }

    // --- out store after flag (drains during next poll window) ---
    {
      size_t oi = (size_t)(gb*TT + tt)*1024 + dir*512 + jb*CPW + gj0;
      if (outf32) {
        f32x2 ov; ov.x = hv0; ov.y = hv1;
        __builtin_nontemporal_store(ov, (f32x2*)((float*)out + oi));
      } else {
        __builtin_nontemporal_store(pv, (u32*)((u16*)out + oi));
      }
    }
  }
}

// ---------------- host ----------------
extern "C" void kernel_launch(void* const* d_in, const int* in_sizes, int n_in,
                              void* d_out, int out_size, void* d_ws, size_t ws_size,
                              hipStream_t stream) {
  (void)in_sizes; (void)n_in; (void)out_size;
  const float* x    = (const float*)d_in[0];
  const float* wih0 = (const float*)d_in[1];
  const float* whh0 = (const float*)d_in[2];
  const float* bih0 = (const float*)d_in[3];
  const float* bhh0 = (const float*)d_in[4];
  const float* wih1 = (const float*)d_in[5];
  const float* whh1 = (const float*)d_in[6];
  const float* bih1 = (const float*)d_in[7];
  const float* bhh1 = (const float*)d_in[8];

  char* ws = (char*)d_ws;
  size_t off = 0;
  auto alloc = [&](size_t bytes) { size_t o = off; off += (bytes + 255) & ~(size_t)255; return o; };
  size_t off_xb   = alloc((size_t)MM * 512 * 2);       // x bf16
  size_t off_wih0 = alloc((size_t)3072 * 512 * 2);
  size_t off_wih1 = alloc((size_t)3072 * 1024 * 2);
  size_t off_whh0 = alloc((size_t)3072 * 512 * 2);
  size_t off_whh1 = alloc((size_t)3072 * 512 * 2);
  size_t off_h0   = alloc((size_t)MM * 1024 * 2);      // layer-0 output bf16
  size_t off_sync = alloc(131072 + 4096);              // h images (128KB) + flags
  size_t off_gx   = off;                               // gx last
  int gxf32 = (ws_size >= off_gx + (size_t)MM * NG * 4) ? 1 : 0;

  u16* xb    = (u16*)(ws + off_xb);
  u16* wih0b = (u16*)(ws + off_wih0);
  u16* wih1b = (u16*)(ws + off_wih1);
  u16* whh0b = (u16*)(ws + off_whh0);
  u16* whh1b = (u16*)(ws + off_whh1);
  u16* h0b   = (u16*)(ws + off_h0);
  u16* himg  = (u16*)(ws + off_sync);
  u32* flags = (u32*)(ws + off_sync + 131072);
  char* gx   = ws + off_gx;

  cvt_bf16<<<4096, 256, 0, stream>>>(x,    xb,    MM*512/8);
  cvt_bf16<<<768,  256, 0, stream>>>(wih0, wih0b, 3072*512/8);
  cvt_bf16<<<1536, 256, 0, stream>>>(wih1, wih1b, 3072*1024/8);
  cvt_bf16<<<768,  256, 0, stream>>>(whh0, whh0b, 3072*512/8);
  cvt_bf16<<<768,  256, 0, stream>>>(whh1, whh1b, 3072*512/8);

  dim3 ggrid(NG/128, MM/128);   // (24, 128)

  // layer 0
  gemm_gx<<<ggrid, 256, 0, stream>>>(xb, wih0b, gx, 512, gxf32);
  (void)hipMemsetAsync(ws + off_sync, 0, 131072 + 4096, stream);
  bigru_rec<<<32, 512, 0, stream>>>(gx, whh0b, bih0, bhh0, (char*)h0b, himg, flags, gxf32, 0);

  // layer 1
  gemm_gx<<<ggrid, 256, 0, stream>>>(h0b, wih1b, gx, 1024, gxf32);
  (void)hipMemsetAsync(ws + off_sync, 0, 131072 + 4096, stream);
  bigru_rec<<<32, 512, 0, stream>>>(gx, whh1b, bih1, bhh1, (char*)d_out, himg, flags, gxf32, 1);
}

// Round 9
// 4662.073 us; speedup vs baseline: 2.8372x; 1.0884x over previous
//
#include <hip/hip_runtime.h>
#include <hip/hip_bf16.h>
#include <stdint.h>

#define TT 512
#define HD 512
#define BB 32
#define MM (BB*TT)     // 16384 rows (b*T+t)
#define NG 3072        // 2 dirs * 3 gates * 512
#define WGD 16         // workgroups per direction
#define CPW 32         // h columns per workgroup

typedef short short8 __attribute__((ext_vector_type(8)));
typedef float f32x4 __attribute__((ext_vector_type(4)));
typedef float f32x2 __attribute__((ext_vector_type(2)));
typedef unsigned short u16;
typedef unsigned int u32;
typedef unsigned long long u64;

__device__ __forceinline__ u16 f2bf(float f) {
  __hip_bfloat16 h = __float2bfloat16(f);
  union { __hip_bfloat16 h; u16 u; } c; c.h = h; return c.u;
}
__device__ __forceinline__ float bf2f(u16 u) {
  union { u32 i; float f; } c; c.i = ((u32)u) << 16; return c.f;
}
__device__ __forceinline__ float sigmf(float x) {
  return 1.0f / (1.0f + __expf(-x));
}
__device__ __forceinline__ float tanhff(float x) {
  float a = __expf(2.0f * x);          // inf -> 1, 0 -> -1 : graceful
  return 1.0f - 2.0f / (a + 1.0f);
}

// ---------------- f32 -> bf16 convert ----------------
__global__ __launch_bounds__(256) void cvt_bf16(const float* __restrict__ in,
                                                u16* __restrict__ out, int n8) {
  int i = blockIdx.x * 256 + threadIdx.x;
  if (i >= n8) return;
  const float4* p = (const float4*)in;
  float4 a = p[2*i], b = p[2*i+1];
  union { short8 v; u16 u[8]; } o;
  o.u[0]=f2bf(a.x); o.u[1]=f2bf(a.y); o.u[2]=f2bf(a.z); o.u[3]=f2bf(a.w);
  o.u[4]=f2bf(b.x); o.u[5]=f2bf(b.y); o.u[6]=f2bf(b.z); o.u[7]=f2bf(b.w);
  ((short8*)out)[i] = o.v;
}

// ---------------- gx GEMM (unchanged) ----------------
__global__ __launch_bounds__(256) void gemm_gx(const u16* __restrict__ A,
                                               const u16* __restrict__ Bw,
                                               char* __restrict__ gxout,
                                               int K, int gxf32) {
  __shared__ __align__(16) u16 lA[128*32];
  __shared__ __align__(16) u16 lB[128*32];
  const int tid = threadIdx.x;
  const int lane = tid & 63;
  const int wid = tid >> 6;
  const int wr = wid >> 1, wc = wid & 1;
  const int bm = blockIdx.y * 128, bn = blockIdx.x * 128;
  const int col = lane & 15, kg = lane >> 4;

  f32x4 acc[4][4];
#pragma unroll
  for (int m = 0; m < 4; ++m)
#pragma unroll
    for (int n = 0; n < 4; ++n) acc[m][n] = (f32x4){0.f,0.f,0.f,0.f};

  const int nkt = K >> 5;
  for (int kt = 0; kt < nkt; ++kt) {
    short8 ra[2], rb[2];
    const int kb = kt * 32;
#pragma unroll
    for (int p = 0; p < 2; ++p) {
      int id = p*256 + tid;
      int row = id >> 2, c = id & 3;
      ra[p] = *(const short8*)(A  + (size_t)(bm+row)*K + kb + c*8);
      rb[p] = *(const short8*)(Bw + (size_t)(bn+row)*K + kb + c*8);
    }
    __syncthreads();
#pragma unroll
    for (int p = 0; p < 2; ++p) {
      int id = p*256 + tid;
      int row = id >> 2, c = id & 3;
      int off = row*64 + ((c ^ ((row>>1)&3))*16);
      *(short8*)((char*)lA + off) = ra[p];
      *(short8*)((char*)lB + off) = rb[p];
    }
    __syncthreads();
    short8 af[4], bf[4];
#pragma unroll
    for (int m = 0; m < 4; ++m) {
      int row = wr*64 + m*16 + col;
      af[m] = *(short8*)((char*)lA + row*64 + ((kg ^ ((row>>1)&3))*16));
    }
#pragma unroll
    for (int n = 0; n < 4; ++n) {
      int row = wc*64 + n*16 + col;
      bf[n] = *(short8*)((char*)lB + row*64 + ((kg ^ ((row>>1)&3))*16));
    }
#pragma unroll
    for (int m = 0; m < 4; ++m)
#pragma unroll
      for (int n = 0; n < 4; ++n)
        acc[m][n] = __builtin_amdgcn_mfma_f32_16x16x32_bf16(af[m], bf[n], acc[m][n], 0,0,0);
  }
#pragma unroll
  for (int m = 0; m < 4; ++m)
#pragma unroll
    for (int n = 0; n < 4; ++n)
#pragma unroll
      for (int r = 0; r < 4; ++r) {
        int rowg = bm + wr*64 + m*16 + kg*4 + r;
        int colg = bn + wc*64 + n*16 + col;
        float v = acc[m][n][r];
        if (gxf32) ((float*)gxout)[(size_t)rowg*NG + colg] = v;
        else       ((u16*)gxout)[(size_t)rowg*NG + colg] = f2bf(v);
      }
}

// ---------------- persistent BiGRU recurrence (pipelined per-producer reads) ----
// grid = 32 WGs (512 thr, 8 waves): dir = wg>>4, jb = wg&15 -> cols [jb*32,+32).
// Wave w polls producers p=w and p=w+8 individually and reads each 2KB slice the
// moment its flag lands. sched_barrier+memory clobber pins the relaxed slice
// loads after the relaxed poll (compiler-level; HW then orders via in-order
// VMEM issue). R7/R8's failure was a gx staging index bug (16 chunks/gate-row
// instead of 8), fixed here: 768 float4 chunks, b=cid/24, g=(cid%24)>>3, q=cid&7.
__global__ __launch_bounds__(512, 2) void bigru_rec(const char* __restrict__ gx,
                                                    const u16* __restrict__ whhb,
                                                    const float* __restrict__ b_ih,
                                                    const float* __restrict__ b_hh,
                                                    char* __restrict__ out,
                                                    u16* __restrict__ himg,   // [2][2][32][512]
                                                    u32* __restrict__ flags,  // [2][16] stride 16 dwords
                                                    int gxf32, int outf32) {
  const int wg = blockIdx.x;
  const int dir = wg >> 4;
  const int jb = wg & 15;
  const int tid = threadIdx.x;
  const int lane = tid & 63;
  const int wv = tid >> 6;
  const int col = lane & 15, kg = lane >> 4;

  __shared__ __align__(16) u16 hstage[32*512];     // 32 KB, swizzled
  __shared__ float gh[3][32][33];                  // padded: no bank conflicts
  __shared__ __align__(16) char gxmem[2][12288];   // 24 KB, parity dbuf (f32 or bf16)
  __shared__ float bihs[3][32], bhhs[3][32];
  __shared__ u32 lctr;

  // --- one-time: w_hh B-fragments (waves 0..5: gate g=wv>>1, half ch=wv&1) ---
  short8 bfrag[16];
  if (wv < 6) {
    const int g = wv >> 1, ch = wv & 1;
    const u16* wrow = whhb + (size_t)(dir*1536 + g*512 + jb*CPW + ch*16 + col) * 512;
#pragma unroll
    for (int kc = 0; kc < 16; ++kc)
      bfrag[kc] = *(const short8*)(wrow + kc*32 + kg*8);
  }
  if (tid < 96) {
    int g = tid >> 5, j = tid & 31;
    bihs[g][j] = b_ih[dir*1536 + g*512 + jb*CPW + j];
    bhhs[g][j] = b_hh[dir*1536 + g*512 + jb*CPW + j];
  }
  if (tid == 0) lctr = 0;
  __syncthreads();

  const int gb = tid >> 4, gj0 = (tid & 15) * 2;
  float hp0 = 0.f, hp1 = 0.f;

  u32* dirflags = flags + (size_t)dir * WGD * 16;
  u32* myflag = dirflags + (size_t)jb * 16;

  // slice-read lane mapping: row = lane>>1, 32B group g4 = (lane&1)*4
  const int srow = lane >> 1, sg4 = (lane & 1) * 4;
  const int p0 = wv, p1 = wv + 8;
  const u32* fp0 = dirflags + (size_t)p0 * 16;
  const u32* fp1 = dirflags + (size_t)p1 * 16;

  for (int t = 0; t < TT; ++t) {
    const int tt = dir ? (TT - 1 - t) : t;
    const int par = t & 1;
    float* gxlF = (float*)gxmem[par];
    u16*   gxlB = (u16*)gxmem[par];

    // --- issue gx[tt] loads into regs (retire under the polls) ---
    // f32: 768 float4 chunks = 32 b x 3 gates x 8 chunks (8 x 4 floats = 32 cols)
    float4 g0, g1; short8 gb16;
    int c0_b=0,c0_g=0,c0_q=0, c1_b=0,c1_g=0,c1_q=0;
    int b16_b=0,b16_g=0,b16_q=0;
    if (gxf32) {
      const float* gxf = (const float*)gx;
      { int cid = tid;      c0_b=cid/24; int r=cid%24; c0_g=r>>3; c0_q=r&7;
        g0 = *(const float4*)(gxf + (size_t)(c0_b*TT+tt)*NG + dir*1536 + c0_g*512 + jb*CPW + c0_q*4); }
      if (tid < 256) {
        int cid = 512+tid;  c1_b=cid/24; int r=cid%24; c1_g=r>>3; c1_q=r&7;
        g1 = *(const float4*)(gxf + (size_t)(c1_b*TT+tt)*NG + dir*1536 + c1_g*512 + jb*CPW + c1_q*4); }
    } else {
      if (tid < 384) {
        const u16* gxb = (const u16*)gx;
        b16_b = tid/12; int r = tid%12; b16_g = r>>2; b16_q = r&3;
        gb16 = *(const short8*)(gxb + (size_t)(b16_b*TT+tt)*NG + dir*1536 + b16_g*512 + jb*CPW + b16_q*8);
      }
    }

    // --- pipelined per-producer poll + slice read (2KB each) ---
    const u64* imgr = (const u64*)(himg + ((size_t)dir*2 + par) * 32 * 512);
    u64 v0[4], v1[4];
    if (t > 0) {
      const u32 need = (u32)t;
      int it = 0;
      while (__hip_atomic_load(fp0, __ATOMIC_RELAXED, __HIP_MEMORY_SCOPE_AGENT) < need && it++ < (1<<24)) {}
    }
    __builtin_amdgcn_sched_barrier(0);
    asm volatile("" ::: "memory");   // pin slice loads AFTER the poll (compiler fence)
#pragma unroll
    for (int j = 0; j < 4; ++j)
      v0[j] = __hip_atomic_load(imgr + srow*128 + p0*8 + sg4 + j, __ATOMIC_RELAXED, __HIP_MEMORY_SCOPE_AGENT);
    if (t > 0) {
      const u32 need = (u32)t;
      int it = 0;
      while (__hip_atomic_load(fp1, __ATOMIC_RELAXED, __HIP_MEMORY_SCOPE_AGENT) < need && it++ < (1<<24)) {}
    }
    __builtin_amdgcn_sched_barrier(0);
    asm volatile("" ::: "memory");   // pin slice loads AFTER the poll (compiler fence)
#pragma unroll
    for (int j = 0; j < 4; ++j)
      v1[j] = __hip_atomic_load(imgr + srow*128 + p1*8 + sg4 + j, __ATOMIC_RELAXED, __HIP_MEMORY_SCOPE_AGENT);

    // --- LDS writes: slices (swizzled) + gx ---
#pragma unroll
    for (int j = 0; j < 4; ++j) {
      int d2 = p0*8 + sg4 + j; int c = d2 >> 1;
      *(u64*)((char*)hstage + srow*1024 + (((c ^ (srow & 7)) << 4) | ((d2 & 1) << 3))) = v0[j];
    }
#pragma unroll
    for (int j = 0; j < 4; ++j) {
      int d2 = p1*8 + sg4 + j; int c = d2 >> 1;
      *(u64*)((char*)hstage + srow*1024 + (((c ^ (srow & 7)) << 4) | ((d2 & 1) << 3))) = v1[j];
    }
    if (gxf32) {
      *(float4*)&gxlF[c0_g*1024 + c0_b*32 + c0_q*4] = g0;
      if (tid < 256) *(float4*)&gxlF[c1_g*1024 + c1_b*32 + c1_q*4] = g1;
    } else {
      if (tid < 384) *(short8*)&gxlB[b16_g*1024 + b16_b*32 + b16_q*8] = gb16;
    }
    __syncthreads();   // (B) hstage + gx staged by all waves

    // --- MFMA: gh[g][b][jloc] over K=512 (waves 0..5) ---
    if (wv < 6) {
      const int g = wv >> 1, ch = wv & 1;
      f32x4 acc0 = (f32x4){0.f,0.f,0.f,0.f};
      f32x4 acc1 = (f32x4){0.f,0.f,0.f,0.f};
#pragma unroll
      for (int kc = 0; kc < 16; ++kc) {
        int c = kc*4 + kg;
        short8 a0 = *(short8*)((char*)hstage + col*1024      + ((c ^ (col & 7)) << 4));
        short8 a1 = *(short8*)((char*)hstage + (16+col)*1024 + ((c ^ (col & 7)) << 4));
        acc0 = __builtin_amdgcn_mfma_f32_16x16x32_bf16(a0, bfrag[kc], acc0, 0,0,0);
        acc1 = __builtin_amdgcn_mfma_f32_16x16x32_bf16(a1, bfrag[kc], acc1, 0,0,0);
      }
#pragma unroll
      for (int r = 0; r < 4; ++r) {
        gh[g][kg*4 + r][ch*16 + col]      = acc0[r];
        gh[g][16 + kg*4 + r][ch*16 + col] = acc1[r];
      }
    }
    __syncthreads();   // (C)

    // --- gates: thread -> (b=gb, j=gj0, gj0+1) ---
    float hv0, hv1; u32 pv;
    {
      float xr0, xz0, xn0, xr1, xz1, xn1;
      if (gxf32) {
        xr0 = gxlF[gb*32+gj0];        xz0 = gxlF[1024+gb*32+gj0];   xn0 = gxlF[2048+gb*32+gj0];
        xr1 = gxlF[gb*32+gj0+1];      xz1 = gxlF[1024+gb*32+gj0+1]; xn1 = gxlF[2048+gb*32+gj0+1];
      } else {
        xr0 = bf2f(gxlB[gb*32+gj0]);   xz0 = bf2f(gxlB[1024+gb*32+gj0]);   xn0 = bf2f(gxlB[2048+gb*32+gj0]);
        xr1 = bf2f(gxlB[gb*32+gj0+1]); xz1 = bf2f(gxlB[1024+gb*32+gj0+1]); xn1 = bf2f(gxlB[2048+gb*32+gj0+1]);
      }
      float r0 = sigmf(xr0 + bihs[0][gj0]   + gh[0][gb][gj0]   + bhhs[0][gj0]);
      float z0 = sigmf(xz0 + bihs[1][gj0]   + gh[1][gb][gj0]   + bhhs[1][gj0]);
      float n0 = tanhff(xn0 + bihs[2][gj0]  + r0*(gh[2][gb][gj0] + bhhs[2][gj0]));
      hv0 = (1.f - z0)*n0 + z0*hp0;
      float r1 = sigmf(xr1 + bihs[0][gj0+1] + gh[0][gb][gj0+1] + bhhs[0][gj0+1]);
      float z1 = sigmf(xz1 + bihs[1][gj0+1] + gh[1][gb][gj0+1] + bhhs[1][gj0+1]);
      float n1 = tanhff(xn1 + bihs[2][gj0+1] + r1*(gh[2][gb][gj0+1] + bhhs[2][gj0+1]));
      hv1 = (1.f - z1)*n1 + z1*hp1;
      hp0 = hv0; hp1 = hv1;

      // publish h_new pair to next image (agent -> LLC)
      u32* img2 = (u32*)(himg + ((size_t)dir*2 + ((t + 1) & 1)) * 32 * 512);
      pv = (u32)f2bf(hv0) | ((u32)f2bf(hv1) << 16);
      __hip_atomic_store(img2 + gb*256 + jb*16 + (tid & 15), pv,
                         __ATOMIC_RELAXED, __HIP_MEMORY_SCOPE_AGENT);
    }

    // --- per-wave drain (parallel) -> LDS counter -> 8th wave releases WG flag ---
    asm volatile("s_waitcnt vmcnt(0)" ::: "memory");
    if (lane == 0) {
      u32 old = atomicAdd(&lctr, 1u);
      if (old == (u32)(t*8 + 7))
        __hip_atomic_store(myflag, (u32)(t + 1), __ATOMIC_RELAXED, __HIP_MEMORY_SCOPE_AGENT);
    }

    // --- out store after flag (drains during next poll window) ---
    {
      size_t oi = (size_t)(gb*TT + tt)*1024 + dir*512 + jb*CPW + gj0;
      if (outf32) {
        f32x2 ov; ov.x = hv0; ov.y = hv1;
        __builtin_nontemporal_store(ov, (f32x2*)((float*)out + oi));
      } else {
        __builtin_nontemporal_store(pv, (u32*)((u16*)out + oi));
      }
    }
  }
}

// ---------------- host ----------------
extern "C" void kernel_launch(void* const* d_in, const int* in_sizes, int n_in,
                              void* d_out, int out_size, void* d_ws, size_t ws_size,
                              hipStream_t stream) {
  (void)in_sizes; (void)n_in; (void)out_size;
  const float* x    = (const float*)d_in[0];
  const float* wih0 = (const float*)d_in[1];
  const float* whh0 = (const float*)d_in[2];
  const float* bih0 = (const float*)d_in[3];
  const float* bhh0 = (const float*)d_in[4];
  const float* wih1 = (const float*)d_in[5];
  const float* whh1 = (const float*)d_in[6];
  const float* bih1 = (const float*)d_in[7];
  const float* bhh1 = (const float*)d_in[8];

  char* ws = (char*)d_ws;
  size_t off = 0;
  auto alloc = [&](size_t bytes) { size_t o = off; off += (bytes + 255) & ~(size_t)255; return o; };
  size_t off_xb   = alloc((size_t)MM * 512 * 2);       // x bf16
  size_t off_wih0 = alloc((size_t)3072 * 512 * 2);
  size_t off_wih1 = alloc((size_t)3072 * 1024 * 2);
  size_t off_whh0 = alloc((size_t)3072 * 512 * 2);
  size_t off_whh1 = alloc((size_t)3072 * 512 * 2);
  size_t off_h0   = alloc((size_t)MM * 1024 * 2);      // layer-0 output bf16
  size_t off_sync = alloc(131072 + 4096);              // h images (128KB) + flags
  size_t off_gx   = off;                               // gx last
  int gxf32 = (ws_size >= off_gx + (size_t)MM * NG * 4) ? 1 : 0;

  u16* xb    = (u16*)(ws + off_xb);
  u16* wih0b = (u16*)(ws + off_wih0);
  u16* wih1b = (u16*)(ws + off_wih1);
  u16* whh0b = (u16*)(ws + off_whh0);
  u16* whh1b = (u16*)(ws + off_whh1);
  u16* h0b   = (u16*)(ws + off_h0);
  u16* himg  = (u16*)(ws + off_sync);
  u32* flags = (u32*)(ws + off_sync + 131072);
  char* gx   = ws + off_gx;

  cvt_bf16<<<4096, 256, 0, stream>>>(x,    xb,    MM*512/8);
  cvt_bf16<<<768,  256, 0, stream>>>(wih0, wih0b, 3072*512/8);
  cvt_bf16<<<1536, 256, 0, stream>>>(wih1, wih1b, 3072*1024/8);
  cvt_bf16<<<768,  256, 0, stream>>>(whh0, whh0b, 3072*512/8);
  cvt_bf16<<<768,  256, 0, stream>>>(whh1, whh1b, 3072*512/8);

  dim3 ggrid(NG/128, MM/128);   // (24, 128)

  // layer 0
  gemm_gx<<<ggrid, 256, 0, stream>>>(xb, wih0b, gx, 512, gxf32);
  (void)hipMemsetAsync(ws + off_sync, 0, 131072 + 4096, stream);
  bigru_rec<<<32, 512, 0, stream>>>(gx, whh0b, bih0, bhh0, (char*)h0b, himg, flags, gxf32, 0);

  // layer 1
  gemm_gx<<<ggrid, 256, 0, stream>>>(h0b, wih1b, gx, 1024, gxf32);
  (void)hipMemsetAsync(ws + off_sync, 0, 131072 + 4096, stream);
  bigru_rec<<<32, 512, 0, stream>>>(gx, whh1b, bih1, bhh1, (char*)d_out, himg, flags, gxf32, 1);
}